// Round 4
// baseline (993.194 us; speedup 1.0000x reference)
//
#include <hip/hip_runtime.h>
#include <math.h>

static constexpr int   B_   = 8;
static constexpr int   N_   = 2048;   // points per set
static constexpr int   TPB  = 256;
static constexpr int   TILE = 32;     // rows/cols owned per block
static constexpr int   BPB  = 64;     // blocks per batch
static constexpr int   NBLK = B_ * BPB;   // 512 blocks (= 2/CU, LDS-capped at 2/CU)
static constexpr int   BN   = B_ * N_;
static constexpr float EPS_ = 1e-9f;
static constexpr float LOG2E = 1.4426950408889634f;

// ws layout (floats):
//  X1    [4*BN]   packed xyz1 (x,y,z,|p|^2)
//  X2    [4*BN]   packed xyz2
//  LSCAL [BN]     log2(scale)
//  LSATR [BN]     log2(satr)
//  LWR   [BN]     log2(wr)
//  WR    [BN]     raw wr
//  COSTP [NBLK]   per-(batch,tile) cost partials
//  BAR   [8*64 u32]  per-batch {cnt @+0, gen @+32} generation barriers
#define WS_X1    (ws)
#define WS_X2    (ws + 4*BN)
#define WS_LSCAL (ws + 8*BN)
#define WS_LSATR (ws + 9*BN)
#define WS_LWR   (ws + 10*BN)
#define WS_WR    (ws + 11*BN)
#define WS_COSTP (ws + 12*BN)
#define WS_BARU  ((unsigned*)(ws + 12*BN + NBLK))

__device__ __constant__ float c_lvl[11] = {
    -65536.f*LOG2E, -16384.f*LOG2E, -4096.f*LOG2E, -1024.f*LOG2E,
    -256.f*LOG2E,   -64.f*LOG2E,    -16.f*LOG2E,   -4.f*LOG2E,
    -1.f*LOG2E,     -0.25f*LOG2E,   0.f };

__global__ void __launch_bounds__(TPB)
emd_init(const float* __restrict__ xyz1, const float* __restrict__ xyz2,
         float* __restrict__ ws)
{
    const int idx = blockIdx.x * TPB + threadIdx.x;
    if (idx < BN) {
        float x = xyz1[idx*3], y = xyz1[idx*3+1], z = xyz1[idx*3+2];
        reinterpret_cast<float4*>(WS_X1)[idx] =
            make_float4(x, y, z, fmaf(x,x, fmaf(y,y, z*z)));
        x = xyz2[idx*3]; y = xyz2[idx*3+1]; z = xyz2[idx*3+2];
        reinterpret_cast<float4*>(WS_X2)[idx] =
            make_float4(x, y, z, fmaf(x,x, fmaf(y,y, z*z)));
        WS_LSATR[idx] = 0.f;   // log2(1)
    }
    if (idx < 8 * 64) WS_BARU[idx] = 0u;   // barrier counters + generations
}

// per-batch 64-block generation barrier (agent-scope release/acquire)
__device__ __forceinline__ void bbar(unsigned* cnt, unsigned* gen, unsigned target)
{
    __syncthreads();
    if (threadIdx.x == 0) {
        __threadfence();   // agent fence: make prior block writes visible
        unsigned prev = __hip_atomic_fetch_add(cnt, 1u, __ATOMIC_ACQ_REL,
                                               __HIP_MEMORY_SCOPE_AGENT);
        if (prev == BPB - 1) {
            __hip_atomic_store(cnt, 0u, __ATOMIC_RELAXED, __HIP_MEMORY_SCOPE_AGENT);
            __hip_atomic_fetch_add(gen, 1u, __ATOMIC_ACQ_REL, __HIP_MEMORY_SCOPE_AGENT);
        } else {
            int spins = 0;
            while (__hip_atomic_load(gen, __ATOMIC_ACQUIRE,
                                     __HIP_MEMORY_SCOPE_AGENT) < target) {
                __builtin_amdgcn_s_sleep(1);
                if (++spins > (1 << 26)) break;   // deadlock bailout (no hang)
            }
        }
        __threadfence();
    }
    __syncthreads();
}

// MODE 0/1: s1 += exp2(kx*px+ky*py+kz*pz + kq + auxA)          (prefolded lvl)
// MODE 2  : raw dotq; s1 += eA, s2 += eA*sqrt(d2), s3 += eB
// MODE 3  : s2 += auxA * sqrt(d2)      (lvl = 0, weight raw)
template<int MODE>
__device__ __forceinline__ void sweep(
    const float4* pts, const float* auxA, const float* auxB,
    const float (&kx)[8], const float (&ky)[8], const float (&kz)[8],
    const float (&kq)[8], float lvlA, float lvlB, int c,
    float (&s1)[8], float (&s2)[8], float (&s3)[8])
{
    for (int i = 0; i < 32; ++i) {
        const int l = c + (i << 6);
        const float4 p = pts[l];
        const float  wA = auxA[l];
        float wB = 0.f;
        if (MODE == 2) wB = auxB[l];
#pragma unroll
        for (int j = 0; j < 8; ++j) {
            if (MODE == 0 || MODE == 1) {
                const float arg = fmaf(kx[j], p.x, fmaf(ky[j], p.y,
                                  fmaf(kz[j], p.z, wA + kq[j])));
                s1[j] += __builtin_amdgcn_exp2f(arg);
            } else if (MODE == 2) {
                const float dotq = fmaf(kx[j], p.x, fmaf(ky[j], p.y,
                                   fmaf(kz[j], p.z, kq[j])));
                const float sq = __builtin_amdgcn_sqrtf(fmaxf(p.w + dotq, 0.f));
                const float eA = __builtin_amdgcn_exp2f(fmaf(lvlA, dotq, wA));
                const float eB = __builtin_amdgcn_exp2f(fmaf(lvlB, dotq, wB));
                s1[j] += eA;
                s2[j]  = fmaf(eA, sq, s2[j]);
                s3[j] += eB;
            } else {
                const float dotq = fmaf(kx[j], p.x, fmaf(ky[j], p.y,
                                   fmaf(kz[j], p.z, kq[j])));
                const float sq = __builtin_amdgcn_sqrtf(fmaxf(p.w + dotq, 0.f));
                s2[j] = fmaf(wA, sq, s2[j]);
            }
        }
    }
}

__global__ void __launch_bounds__(TPB, 2)
emd_main(float* __restrict__ ws, float* __restrict__ out)
{
    __shared__ float4 pts[N_];          // 32 KB
    __shared__ float  auxA[N_];         // 8 KB
    __shared__ float  auxB[N_];         // 8 KB
    __shared__ float  red[64][33];      // 8.4 KB
    __shared__ float  red2[8][33];      // 1 KB

    const int b    = blockIdx.x >> 6;
    const int tile = blockIdx.x & 63;
    const int t    = threadIdx.x;
    const int g    = t & 3;             // owned group: 4 x 8
    const int c    = t >> 2;            // stream chunk: 64 x 32

    unsigned* bcnt = WS_BARU + b * 64;
    unsigned* bgen = bcnt + 32;         // separate 128B cacheline
    unsigned  mygen = 0;

    const float4* x1v = reinterpret_cast<const float4*>(WS_X1) + b * N_;
    const float4* x2v = reinterpret_cast<const float4*>(WS_X2) + b * N_;
    const float* lscal = WS_LSCAL + b * N_;
    const float* lsatr = WS_LSATR + b * N_;
    const float* lwr   = WS_LWR   + b * N_;
    const float* wrr   = WS_WR    + b * N_;

    // owned coords: rows (set 1) and cols (set 2), as -2x,-2y,-2z,|q|^2
    float rx[8], ry[8], rz[8], rq[8], ox[8], oy[8], oz[8], oq[8];
    {
        const int ob = tile * TILE + g * 8;
#pragma unroll
        for (int j = 0; j < 8; ++j) {
            float4 v = x1v[ob + j];
            rx[j] = -2.f*v.x; ry[j] = -2.f*v.y; rz[j] = -2.f*v.z; rq[j] = v.w;
            float4 w = x2v[ob + j];
            ox[j] = -2.f*w.x; oy[j] = -2.f*w.y; oz[j] = -2.f*w.z; oq[j] = w.w;
        }
    }

    float satl = 1.f, satr = 1.f, mysc = 0.f, cost = 0.f;   // valid t<32
    const int gidx = b * N_ + tile * TILE + t;              // t<32 epilogue idx
    float s1[8], s2[8], s3[8];
    float kx[8], ky[8], kz[8], kq[8];

#define ZERO3() _Pragma("unroll") \
    for (int j = 0; j < 8; ++j) { s1[j] = 0.f; s2[j] = 0.f; s3[j] = 0.f; }

#define REDUCE(arr, dst)                                                   \
    {   _Pragma("unroll")                                                  \
        for (int j = 0; j < 8; ++j) red[c][g * 8 + j] = arr[j];            \
        __syncthreads();                                                   \
        { const int o = t & 31, sg = t >> 5; float a = 0.f;                \
          _Pragma("unroll")                                                \
          for (int k = 0; k < 8; ++k) a += red[sg * 8 + k][o];             \
          red2[sg][o] = a; }                                               \
        __syncthreads();                                                   \
        dst = 0.f;                                                         \
        if (t < TILE) { _Pragma("unroll")                                  \
            for (int sgg = 0; sgg < 8; ++sgg) dst += red2[sgg][t]; }       \
        __syncthreads(); }

    // ================= M0: level-0 row sweep -> scale =================
    {
        const float lv = c_lvl[0];
        for (int p = t; p < N_; p += TPB) {
            float4 v = x2v[p]; pts[p] = v;
            auxA[p] = fmaf(lv, v.w, lsatr[p]);
        }
#pragma unroll
        for (int j = 0; j < 8; ++j) {
            kx[j] = lv*rx[j]; ky[j] = lv*ry[j]; kz[j] = lv*rz[j]; kq[j] = lv*rq[j];
        }
        __syncthreads();
        ZERO3();
        sweep<0>(pts, auxA, auxB, kx, ky, kz, kq, 0.f, 0.f, c, s1, s2, s3);
        float rs1; REDUCE(s1, rs1);
        if (t < TILE) {
            mysc = satl / (rs1 + EPS_);
            WS_LSCAL[gidx] = __log2f(mysc);
        }
        bbar(bcnt, bgen, ++mygen);
    }

    for (int lev = 0; lev <= 10; ++lev) {
        // ========== M1: col sweep at lev -> satr / wr ==========
        {
            const float lv = c_lvl[lev];
            for (int p = t; p < N_; p += TPB) {
                float4 v = x1v[p]; pts[p] = v;
                auxA[p] = fmaf(lv, v.w, lscal[p]);
            }
#pragma unroll
            for (int j = 0; j < 8; ++j) {
                kx[j] = lv*ox[j]; ky[j] = lv*oy[j]; kz[j] = lv*oz[j]; kq[j] = lv*oq[j];
            }
            __syncthreads();
            ZERO3();
            sweep<1>(pts, auxA, auxB, kx, ky, kz, kq, 0.f, 0.f, c, s1, s2, s3);
            float rs1; REDUCE(s1, rs1);
            if (t < TILE) {
                const float w1s = satr * rs1;
                const float rr  = fminf(satr / (w1s + EPS_), 1.f);
                const float wrv = satr * rr;
                satr = fmaxf(satr - rr * w1s, 0.f);
                WS_WR[gidx]    = wrv;
                WS_LWR[gidx]   = __log2f(wrv);
                WS_LSATR[gidx] = __log2f(satr);
            }
            bbar(bcnt, bgen, ++mygen);
        }

        if (lev < 10) {
            // ===== M2: merged P3(lev) + P1(lev+1) row sweep =====
            const float lvA = c_lvl[lev], lvB = c_lvl[lev + 1];
            for (int p = t; p < N_; p += TPB) {
                float4 v = x2v[p]; pts[p] = v;
                auxA[p] = fmaf(lvA, v.w, lwr[p]);
                auxB[p] = fmaf(lvB, v.w, lsatr[p]);
            }
            __syncthreads();
            ZERO3();
            sweep<2>(pts, auxA, auxB, rx, ry, rz, rq, lvA, lvB, c, s1, s2, s3);
            float rs1, rs2, rs3;
            REDUCE(s1, rs1); REDUCE(s2, rs2); REDUCE(s3, rs3);
            if (t < TILE) {
                satl = fmaxf(satl - mysc * rs1, 0.f);
                cost = fmaf(mysc, rs2, cost);
                mysc = satl / (rs3 + EPS_);
                WS_LSCAL[gidx] = __log2f(mysc);
            }
            bbar(bcnt, bgen, ++mygen);
        } else {
            // ===== M3: final row sweep (lvl = 0 -> e = wr) =====
            for (int p = t; p < N_; p += TPB) {
                float4 v = x2v[p]; pts[p] = v;
                auxA[p] = wrr[p];
            }
            __syncthreads();
            ZERO3();
            sweep<3>(pts, auxA, auxB, rx, ry, rz, rq, 0.f, 0.f, c, s1, s2, s3);
            float rs2; REDUCE(s2, rs2);
            if (t < TILE) {
                cost = fmaf(mysc, rs2, cost);
                float v = cost;
#pragma unroll
                for (int k = 16; k >= 1; k >>= 1) v += __shfl_xor(v, k, 64);
                if (t == 0) WS_COSTP[b * BPB + tile] = v;
            }
            bbar(bcnt, bgen, ++mygen);
            if (tile == 0 && t < 64) {
                float v = WS_COSTP[b * BPB + t];
#pragma unroll
                for (int k = 32; k >= 1; k >>= 1) v += __shfl_xor(v, k, 64);
                if (t == 0) out[b] = v;
            }
        }
    }
}

extern "C" void kernel_launch(void* const* d_in, const int* in_sizes, int n_in,
                              void* d_out, int out_size, void* d_ws, size_t ws_size,
                              hipStream_t stream)
{
    const float* xyz1 = (const float*)d_in[0];
    const float* xyz2 = (const float*)d_in[1];
    float* out = (float*)d_out;
    float* ws  = (float*)d_ws;

    emd_init<<<BN / TPB, TPB, 0, stream>>>(xyz1, xyz2, ws);
    emd_main<<<NBLK, TPB, 0, stream>>>(ws, out);
}

// Round 5
// 339.222 us; speedup vs baseline: 2.9279x; 2.9279x over previous
//
#include <hip/hip_runtime.h>
#include <math.h>

static constexpr int   B_   = 8;
static constexpr int   N_   = 2048;   // points per set
static constexpr int   TPB  = 256;
static constexpr int   TILE = 32;                  // rows/cols owned per block
static constexpr int   NBLK = (B_ * N_) / TILE;    // 512 blocks per pass
static constexpr int   BN   = B_ * N_;
static constexpr float EPS_ = 1e-9f;
static constexpr float LOG2E = 1.4426950408889634f;

// ws layout (floats):
//  X1   [4*BN]  packed xyz1 (x,y,z,|p|^2)
//  X2   [4*BN]  packed xyz2
//  SATL [BN]    remaining row capacity
//  SATR [BN]    remaining col capacity
//  SCAL [BN]    raw row scale
//  LSCAL[BN]    log2(scale)
//  WLS  [2*BN]  float2 (log2(wr), log2(satr))
//  WR   [BN]    raw wr
//  COST [BN]    per-row accumulated cost
//  COSTP[NBLK]  per-tile cost partials
#define WS_X1    (ws)
#define WS_X2    (ws + 4*BN)
#define WS_SATL  (ws + 8*BN)
#define WS_SATR  (ws + 9*BN)
#define WS_SCAL  (ws + 10*BN)
#define WS_LSCAL (ws + 11*BN)
#define WS_WLS   (reinterpret_cast<float2*>(ws + 12*BN))
#define WS_WR    (ws + 14*BN)
#define WS_COST  (ws + 15*BN)
#define WS_COSTP (ws + 16*BN)

__global__ void __launch_bounds__(TPB)
emd_init(const float* __restrict__ xyz1, const float* __restrict__ xyz2,
         float* __restrict__ ws)
{
    const int idx = blockIdx.x * TPB + threadIdx.x;
    if (idx >= BN) return;
    float x = xyz1[idx*3], y = xyz1[idx*3+1], z = xyz1[idx*3+2];
    reinterpret_cast<float4*>(WS_X1)[idx] =
        make_float4(x, y, z, fmaf(x,x, fmaf(y,y, z*z)));
    x = xyz2[idx*3]; y = xyz2[idx*3+1]; z = xyz2[idx*3+2];
    reinterpret_cast<float4*>(WS_X2)[idx] =
        make_float4(x, y, z, fmaf(x,x, fmaf(y,y, z*z)));
    WS_SATL[idx] = 1.f;
    WS_SATR[idx] = 1.f;
    WS_COST[idx] = 0.f;
    WS_WLS[idx]  = make_float2(0.f, 0.f);   // (lwr unused yet, log2(satr)=0)
}

// MODE 0: first row sweep  (stream x2, w=lvl*|p|^2+lsatr)  -> scal/lscal
// MODE 1: col sweep        (stream x1, w=lvl*|p|^2+lscal)  -> satr, wr, wls
// MODE 2: P3(lev)+P1(lev+1) row sweep (stream x2, w=|p|^2, aux2=(argA,argB))
//                                                   -> satl, cost, scal/lscal
// MODE 3: final row sweep  (stream x2, w=raw wr)    -> cost partials
template<int MODE>
__global__ void __launch_bounds__(TPB, (MODE == 2) ? 3 : 4)
emd_pass(float* __restrict__ ws, const float lvlA, const float lvlB)
{
    constexpr int SMEM_BYTES = (MODE == 2) ? (32768 + 16384) : 32768;
    __shared__ __align__(16) char smem[SMEM_BYTES];
    float4* pts  = reinterpret_cast<float4*>(smem);
    float2* aux2 = reinterpret_cast<float2*>(smem + 32768);   // MODE 2 only
    // reduction scratch overlays pts (dead after the sweep)
    float (*red)[33]  = reinterpret_cast<float(*)[33]>(smem);
    float (*red2)[33] = reinterpret_cast<float(*)[33]>(smem + 64*33*4);

    const int b    = blockIdx.x >> 6;
    const int tile = blockIdx.x & 63;
    const int t    = threadIdx.x;
    const int g    = t & 3;             // owned group: 4 x 8
    const int c    = t >> 2;            // stream chunk base

    const float4* x1v = reinterpret_cast<const float4*>(WS_X1) + b * N_;
    const float4* x2v = reinterpret_cast<const float4*>(WS_X2) + b * N_;
    const float2* wls = WS_WLS + b * N_;
    const float*  lscal = WS_LSCAL + b * N_;
    const float*  wrp   = WS_WR + b * N_;

    // ---- staging ----
    for (int p = t; p < N_; p += TPB) {
        if (MODE == 0) {
            float4 v = x2v[p];
            pts[p] = make_float4(v.x, v.y, v.z, fmaf(lvlB, v.w, wls[p].y));
        } else if (MODE == 1) {
            float4 v = x1v[p];
            pts[p] = make_float4(v.x, v.y, v.z, fmaf(lvlB, v.w, lscal[p]));
        } else if (MODE == 2) {
            float4 v = x2v[p];
            pts[p] = v;
            float2 q = wls[p];
            aux2[p] = make_float2(fmaf(lvlA, v.w, q.x), fmaf(lvlB, v.w, q.y));
        } else {
            float4 v = x2v[p];
            pts[p] = make_float4(v.x, v.y, v.z, wrp[p]);
        }
    }

    // ---- owned coefficients ----
    const float4* ownv = (MODE == 1) ? x2v : x1v;
    const int ob = tile * TILE + g * 8;
    float kx[8], ky[8], kz[8], kq[8];
#pragma unroll
    for (int j = 0; j < 8; ++j) {
        float4 v = ownv[ob + j];
        if (MODE == 0 || MODE == 1) {
            const float m2lv = -2.f * lvlB;
            kx[j] = m2lv * v.x; ky[j] = m2lv * v.y; kz[j] = m2lv * v.z;
            kq[j] = lvlB * v.w;
        } else if (MODE == 2) {
            kx[j] = -2.f * v.x; ky[j] = -2.f * v.y; kz[j] = -2.f * v.z;
            kq[j] = v.w;
        } else {
            kx[j] = v.x; ky[j] = v.y; kz[j] = v.z; kq[j] = 0.f;
        }
    }
    __syncthreads();

    // ---- sweep (2-deep register prefetch of the streamed point) ----
    float s1[8], s2[8], s3[8];
#pragma unroll
    for (int j = 0; j < 8; ++j) { s1[j] = 0.f; s2[j] = 0.f; s3[j] = 0.f; }

    int l = c;
    float4 p = pts[l];
    float2 a;
    if (MODE == 2) a = aux2[l];

    if (MODE == 0 || MODE == 1) {
#pragma unroll 4
        for (int i = 0; i < 32; ++i) {
            const int ln = (l + 64) & (N_ - 1);
            const float4 pn = pts[ln];
#pragma unroll
            for (int j = 0; j < 8; ++j) {
                const float arg = fmaf(kx[j], p.x, fmaf(ky[j], p.y,
                                  fmaf(kz[j], p.z, p.w + kq[j])));
                s1[j] += __builtin_amdgcn_exp2f(arg);
            }
            p = pn; l = ln;
        }
    } else if (MODE == 2) {
#pragma unroll 2
        for (int i = 0; i < 32; ++i) {
            const int ln = (l + 64) & (N_ - 1);
            const float4 pn = pts[ln];
            const float2 an = aux2[ln];
#pragma unroll
            for (int j = 0; j < 8; ++j) {
                const float dq = fmaf(kx[j], p.x, fmaf(ky[j], p.y,
                                 fmaf(kz[j], p.z, kq[j])));       // dot + |q|^2
                const float d2 = p.w + dq;
                const float sq = __builtin_amdgcn_sqrtf(fmaxf(d2, 0.f));
                const float eA = __builtin_amdgcn_exp2f(fmaf(lvlA, dq, a.x));
                const float eB = __builtin_amdgcn_exp2f(fmaf(lvlB, dq, a.y));
                s1[j] += eA;
                s2[j]  = fmaf(eA, sq, s2[j]);
                s3[j] += eB;
            }
            p = pn; a = an; l = ln;
        }
    } else {
#pragma unroll 4
        for (int i = 0; i < 32; ++i) {
            const int ln = (l + 64) & (N_ - 1);
            const float4 pn = pts[ln];
#pragma unroll
            for (int j = 0; j < 8; ++j) {
                const float dx = p.x - kx[j], dy = p.y - ky[j], dz = p.z - kz[j];
                const float d2 = fmaf(dx, dx, fmaf(dy, dy, dz * dz));
                const float sq = __builtin_amdgcn_sqrtf(fmaxf(d2, 0.f));
                s2[j] = fmaf(p.w, sq, s2[j]);
            }
            p = pn; l = ln;
        }
    }

// two-stage block reduction; leading sync makes the pts->red overlay safe
#define REDUCE(arr, dst)                                                   \
    {   __syncthreads();                                                   \
        _Pragma("unroll")                                                  \
        for (int j = 0; j < 8; ++j) red[c][g * 8 + j] = arr[j];            \
        __syncthreads();                                                   \
        { const int o = t & 31, sg = t >> 5; float a2 = 0.f;               \
          _Pragma("unroll")                                                \
          for (int k = 0; k < 8; ++k) a2 += red[sg * 8 + k][o];            \
          red2[sg][o] = a2; }                                              \
        __syncthreads();                                                   \
        dst = 0.f;                                                         \
        if (t < TILE) { _Pragma("unroll")                                  \
            for (int sgg = 0; sgg < 8; ++sgg) dst += red2[sgg][t]; } }

    const int gidx = b * N_ + tile * TILE + t;   // valid for t < TILE

    if (MODE == 0) {
        float rs1; REDUCE(s1, rs1);
        if (t < TILE) {
            const float sc = WS_SATL[gidx] / (rs1 + EPS_);
            WS_SCAL[gidx]  = sc;
            WS_LSCAL[gidx] = __log2f(sc);
        }
    } else if (MODE == 1) {
        float rs1; REDUCE(s1, rs1);
        if (t < TILE) {
            const float sr  = WS_SATR[gidx];
            const float w1s = sr * rs1;
            const float rr  = fminf(sr / (w1s + EPS_), 1.f);
            const float wrv = sr * rr;
            const float srn = fmaxf(sr - rr * w1s, 0.f);
            WS_SATR[gidx] = srn;
            WS_WR[gidx]   = wrv;
            WS_WLS[gidx + b * N_ * 0] = make_float2(__log2f(wrv), __log2f(srn));
        }
    } else if (MODE == 2) {
        float rs1, rs2, rs3;
        REDUCE(s1, rs1); REDUCE(s2, rs2); REDUCE(s3, rs3);
        if (t < TILE) {
            const float scp = WS_SCAL[gidx];
            const float sln = fmaxf(WS_SATL[gidx] - scp * rs1, 0.f);
            WS_COST[gidx]   = fmaf(scp, rs2, WS_COST[gidx]);
            const float scn = sln / (rs3 + EPS_);
            WS_SATL[gidx]  = sln;
            WS_SCAL[gidx]  = scn;
            WS_LSCAL[gidx] = __log2f(scn);
        }
    } else {
        float rs2; REDUCE(s2, rs2);
        float v = 0.f;
        if (t < TILE)
            v = fmaf(WS_SCAL[gidx], rs2, WS_COST[gidx]);
        if (t < 64) {
#pragma unroll
            for (int k = 16; k >= 1; k >>= 1) v += __shfl_xor(v, k, 64);
            if (t == 0) WS_COSTP[blockIdx.x] = v;
        }
    }
#undef REDUCE
}

__global__ void __launch_bounds__(64)
emd_finish(const float* __restrict__ costp, float* __restrict__ out)
{
    const int b = blockIdx.x;
    const int t = threadIdx.x;
    float v = costp[b * 64 + t];
#pragma unroll
    for (int k = 32; k >= 1; k >>= 1) v += __shfl_xor(v, k, 64);
    if (t == 0) out[b] = v;
}

extern "C" void kernel_launch(void* const* d_in, const int* in_sizes, int n_in,
                              void* d_out, int out_size, void* d_ws, size_t ws_size,
                              hipStream_t stream)
{
    const float* xyz1 = (const float*)d_in[0];
    const float* xyz2 = (const float*)d_in[1];
    float* out = (float*)d_out;
    float* ws  = (float*)d_ws;

    emd_init<<<BN / TPB, TPB, 0, stream>>>(xyz1, xyz2, ws);

    static const float levels[11] = {
        -65536.f, -16384.f, -4096.f, -1024.f, -256.f,
        -64.f, -16.f, -4.f, -1.f, -0.25f, 0.f};

    // level 0: first row sweep + col sweep
    emd_pass<0><<<NBLK, TPB, 0, stream>>>(ws, 0.f, levels[0] * LOG2E);
    emd_pass<1><<<NBLK, TPB, 0, stream>>>(ws, 0.f, levels[0] * LOG2E);
    // levels 1..10: merged P3(prev)+P1(cur) row sweep, then col sweep
    for (int lev = 1; lev < 11; ++lev) {
        emd_pass<2><<<NBLK, TPB, 0, stream>>>(ws, levels[lev-1] * LOG2E,
                                                  levels[lev]   * LOG2E);
        emd_pass<1><<<NBLK, TPB, 0, stream>>>(ws, 0.f, levels[lev] * LOG2E);
    }
    // final P3 at level 10 (lvl = 0 -> weight = raw wr)
    emd_pass<3><<<NBLK, TPB, 0, stream>>>(ws, 0.f, 0.f);

    emd_finish<<<B_, 64, 0, stream>>>(WS_COSTP, out);
}